// Round 1
// baseline (431.250 us; speedup 1.0000x reference)
//
#include <hip/hip_runtime.h>
#include <stdint.h>

#define MASK_ID 50256
#define TOPK 50
#define TOPP 0.9f
#define BLOCK 256

// ---------------- JAX threefry2x32 (20 rounds), key = (0, 42) ----------------
__device__ __forceinline__ uint32_t rotl32(uint32_t x, uint32_t r) {
    return (x << r) | (x >> (32u - r));
}

__device__ uint32_t threefry_0_42(uint32_t x0, uint32_t x1, bool second) {
    const uint32_t ks0 = 0u;
    const uint32_t ks1 = 42u;
    const uint32_t ks2 = 0u ^ 42u ^ 0x1BD11BDAu;
    x0 += ks0; x1 += ks1;
    {   // group 1: rotations [13,15,26,6]
        const uint32_t R[4] = {13u, 15u, 26u, 6u};
        #pragma unroll
        for (int i = 0; i < 4; i++) { x0 += x1; x1 = rotl32(x1, R[i]); x1 ^= x0; }
        x0 += ks1; x1 += ks2 + 1u;
    }
    {   // group 2: rotations [17,29,16,24]
        const uint32_t R[4] = {17u, 29u, 16u, 24u};
        #pragma unroll
        for (int i = 0; i < 4; i++) { x0 += x1; x1 = rotl32(x1, R[i]); x1 ^= x0; }
        x0 += ks2; x1 += ks0 + 2u;
    }
    {   // group 3
        const uint32_t R[4] = {13u, 15u, 26u, 6u};
        #pragma unroll
        for (int i = 0; i < 4; i++) { x0 += x1; x1 = rotl32(x1, R[i]); x1 ^= x0; }
        x0 += ks0; x1 += ks1 + 3u;
    }
    {   // group 4
        const uint32_t R[4] = {17u, 29u, 16u, 24u};
        #pragma unroll
        for (int i = 0; i < 4; i++) { x0 += x1; x1 = rotl32(x1, R[i]); x1 ^= x0; }
        x0 += ks1; x1 += ks2 + 4u;
    }
    {   // group 5
        const uint32_t R[4] = {13u, 15u, 26u, 6u};
        #pragma unroll
        for (int i = 0; i < 4; i++) { x0 += x1; x1 = rotl32(x1, R[i]); x1 ^= x0; }
        x0 += ks2; x1 += ks0 + 5u;
    }
    return second ? x1 : x0;
}

// Gumbel noise at flat index of the (B,S,V) tensor, exactly as
// jax.random.gumbel(key(42), (B,S,V), float32) produces it.
// JAX random_bits: counts = iota(N); split into halves -> bits[i] (i<N/2) is
// out0 of block (i, i+N/2); bits[N/2+i] is out1 of the same block.
__device__ float gumbel_at(unsigned long long flat, unsigned long long total) {
    unsigned long long half = total >> 1;   // total is even (2*1024*50257)
    uint32_t bits;
    if (flat < half) bits = threefry_0_42((uint32_t)flat, (uint32_t)(flat + half), false);
    else             bits = threefry_0_42((uint32_t)(flat - half), (uint32_t)flat, true);
    // uniform in [tiny, 1): f = bitcast((bits>>9)|0x3F800000) - 1 in [0,1)
    float f = __uint_as_float((bits >> 9) | 0x3F800000u) - 1.0f;
    const float tiny = 1.17549435e-38f;     // jnp.finfo(f32).tiny
    float u = fmaxf(tiny, f);               // f*(1-tiny)+tiny rounds to f (or tiny at 0)
    return -logf(-logf(u));
}

// monotone float->uint key: preserves total order of floats
__device__ __forceinline__ uint32_t fkey(float x) {
    uint32_t u = __float_as_uint(x);
    return (u & 0x80000000u) ? ~u : (u | 0x80000000u);
}

__global__ __launch_bounds__(BLOCK)
void rd_kernel(const float* __restrict__ logits, const int* __restrict__ x_t,
               int* __restrict__ out, int V, int rows) {
    const int row = blockIdx.x;
    if (row >= rows) return;
    const int tid = threadIdx.x;
    const int xv = x_t[row];
    if (xv != MASK_ID) {                    // fast path: output = x_t
        if (tid == 0) out[row] = xv;
        return;
    }
    // ---- rare path: full top-k / top-p / categorical for this row ----
    const float* lg = logits + (size_t)row * (size_t)V;

    __shared__ uint32_t hist[256];
    __shared__ uint32_t s_prefix;
    __shared__ int s_remaining;
    __shared__ int n_top;
    __shared__ float tv[TOPK];
    __shared__ int   ti[TOPK];
    __shared__ int   red[BLOCK];

    // 1) radix-select the 50th largest value (as monotone key), MSB-first
    uint32_t prefix = 0u;
    int remaining = TOPK;
    for (int shift = 24; shift >= 0; shift -= 8) {
        hist[tid] = 0u;
        __syncthreads();
        uint32_t pmask = (shift == 24) ? 0u : (0xFFFFFFFFu << (shift + 8));
        for (int v = tid; v < V; v += BLOCK) {
            uint32_t k = fkey(lg[v]);
            if ((k & pmask) == prefix)
                atomicAdd(&hist[(k >> shift) & 0xFFu], 1u);
        }
        __syncthreads();
        if (tid == 0) {
            int cum = 0, b;
            for (b = 255; b >= 0; b--) {
                int c = (int)hist[b];
                if (cum + c >= remaining) break;
                cum += c;
            }
            if (b < 0) b = 0;               // unreachable by construction
            s_prefix = prefix | ((uint32_t)b << shift);
            s_remaining = remaining - cum;
        }
        __syncthreads();
        prefix = s_prefix;
        remaining = s_remaining;
        __syncthreads();
    }
    const uint32_t thresh = prefix;         // key of the 50th-largest value
    const int need_eq = remaining;          // how many ==thresh entries to keep

    // 2) gather strictly-greater entries (count = 50 - need_eq <= 49)
    if (tid == 0) n_top = 0;
    __syncthreads();
    for (int v = tid; v < V; v += BLOCK) {
        float x = lg[v];
        if (fkey(x) > thresh) {
            int p = atomicAdd(&n_top, 1);
            tv[p] = x; ti[p] = v;
        }
    }
    __syncthreads();
    const int base = n_top;
    // equals, by ascending index (matches lax.top_k tie-break)
    int last = -1;
    for (int j = 0; j < need_eq; j++) {
        int best = V;
        for (int v = tid; v < V; v += BLOCK) {
            if (v > last && fkey(lg[v]) == thresh) { best = v; break; }
        }
        red[tid] = best;
        __syncthreads();
        for (int s = BLOCK / 2; s > 0; s >>= 1) {
            if (tid < s) red[tid] = min(red[tid], red[tid + s]);
            __syncthreads();
        }
        int found = red[0];
        if (tid == 0) { tv[base + j] = lg[found]; ti[base + j] = found; }
        last = found;
        __syncthreads();
    }

    // 3) single-thread epilogue: sort 50, softmax+top-p, gumbel-argmax
    if (tid == 0) {
        // insertion sort: value desc, index asc on ties (stable argsort(-x))
        for (int i = 1; i < TOPK; i++) {
            float v = tv[i]; int id = ti[i];
            int j = i - 1;
            while (j >= 0 && (tv[j] < v || (tv[j] == v && ti[j] > id))) {
                tv[j + 1] = tv[j]; ti[j + 1] = ti[j]; j--;
            }
            tv[j + 1] = v; ti[j + 1] = id;
        }
        float m = tv[0];
        float sum = 0.0f;
        for (int i = 0; i < TOPK; i++) sum += expf(tv[i] - m);
        const unsigned long long total = (unsigned long long)rows * (unsigned long long)V;
        float cum = 0.0f;               // exclusive cumsum of probs
        float best = -INFINITY;
        int bestv = 0x7fffffff;
        for (int i = 0; i < TOPK; i++) {
            bool keep = (i == 0) || (cum <= TOPP);   // remove iff cum[j-1] > p
            cum += expf(tv[i] - m) / sum;
            if (!keep) continue;
            unsigned long long flat = (unsigned long long)row * (unsigned long long)V
                                      + (unsigned long long)ti[i];
            float g = gumbel_at(flat, total);
            float s = tv[i] + g;
            if (s > best || (s == best && ti[i] < bestv)) { best = s; bestv = ti[i]; }
        }
        out[row] = bestv;
    }
}

extern "C" void kernel_launch(void* const* d_in, const int* in_sizes, int n_in,
                              void* d_out, int out_size, void* d_ws, size_t ws_size,
                              hipStream_t stream) {
    const float* logits = (const float*)d_in[0];
    const int*   x_t    = (const int*)d_in[1];
    int*         out    = (int*)d_out;
    const int rows = in_sizes[1];                 // B*S = 2048
    const int V    = in_sizes[0] / rows;          // 50257
    rd_kernel<<<rows, BLOCK, 0, stream>>>(logits, x_t, out, V, rows);
}

// Round 2
// 429.550 us; speedup vs baseline: 1.0040x; 1.0040x over previous
//
#include <hip/hip_runtime.h>
#include <stdint.h>

#define MASK_ID 50256
#define TOPK 50
#define TOPP 0.9f
#define BLOCK 256
#define GRID 64          // 2048 rows / 64 blocks = 32 rows per block

// ---------------- JAX threefry2x32 (20 rounds), key = (0, 42) ----------------
__device__ __forceinline__ uint32_t rotl32(uint32_t x, uint32_t r) {
    return (x << r) | (x >> (32u - r));
}

__device__ uint32_t threefry_0_42(uint32_t x0, uint32_t x1, bool second) {
    const uint32_t ks0 = 0u;
    const uint32_t ks1 = 42u;
    const uint32_t ks2 = 0u ^ 42u ^ 0x1BD11BDAu;
    x0 += ks0; x1 += ks1;
    {
        const uint32_t R[4] = {13u, 15u, 26u, 6u};
        #pragma unroll
        for (int i = 0; i < 4; i++) { x0 += x1; x1 = rotl32(x1, R[i]); x1 ^= x0; }
        x0 += ks1; x1 += ks2 + 1u;
    }
    {
        const uint32_t R[4] = {17u, 29u, 16u, 24u};
        #pragma unroll
        for (int i = 0; i < 4; i++) { x0 += x1; x1 = rotl32(x1, R[i]); x1 ^= x0; }
        x0 += ks2; x1 += ks0 + 2u;
    }
    {
        const uint32_t R[4] = {13u, 15u, 26u, 6u};
        #pragma unroll
        for (int i = 0; i < 4; i++) { x0 += x1; x1 = rotl32(x1, R[i]); x1 ^= x0; }
        x0 += ks0; x1 += ks1 + 3u;
    }
    {
        const uint32_t R[4] = {17u, 29u, 16u, 24u};
        #pragma unroll
        for (int i = 0; i < 4; i++) { x0 += x1; x1 = rotl32(x1, R[i]); x1 ^= x0; }
        x0 += ks1; x1 += ks2 + 4u;
    }
    {
        const uint32_t R[4] = {13u, 15u, 26u, 6u};
        #pragma unroll
        for (int i = 0; i < 4; i++) { x0 += x1; x1 = rotl32(x1, R[i]); x1 ^= x0; }
        x0 += ks2; x1 += ks0 + 5u;
    }
    return second ? x1 : x0;
}

// Gumbel noise at flat index of the (B,S,V) tensor, exactly matching
// jax.random.gumbel(key(42), (B,S,V), float32): counts=iota(N) split in halves.
__device__ float gumbel_at(unsigned long long flat, unsigned long long total) {
    unsigned long long half = total >> 1;   // total is even (2*1024*50257)
    uint32_t bits;
    if (flat < half) bits = threefry_0_42((uint32_t)flat, (uint32_t)(flat + half), false);
    else             bits = threefry_0_42((uint32_t)(flat - half), (uint32_t)flat, true);
    float f = __uint_as_float((bits >> 9) | 0x3F800000u) - 1.0f;
    const float tiny = 1.17549435e-38f;
    float u = fmaxf(tiny, f);
    return -logf(-logf(u));
}

// monotone float->uint key: preserves total order of floats
__device__ __forceinline__ uint32_t fkey(float x) {
    uint32_t u = __float_as_uint(x);
    return (u & 0x80000000u) ? ~u : (u | 0x80000000u);
}

// Block-cooperative exact pipeline for ONE masked row. All 256 threads enter.
__device__ void process_row(const float* __restrict__ lg, int row, int V, int rows,
                            int* __restrict__ out,
                            uint32_t* hist, int* red, float* tv, int* ti,
                            uint32_t* p_prefix, int* p_remaining, int* p_ntop) {
    const int tid = threadIdx.x;

    // 1) radix-select the 50th-largest value's monotone key, MSB-first
    uint32_t prefix = 0u;
    int remaining = TOPK;
    for (int shift = 24; shift >= 0; shift -= 8) {
        hist[tid] = 0u;
        __syncthreads();
        uint32_t pmask = (shift == 24) ? 0u : (0xFFFFFFFFu << (shift + 8));
        for (int v = tid; v < V; v += BLOCK) {
            uint32_t k = fkey(lg[v]);
            if ((k & pmask) == prefix)
                atomicAdd(&hist[(k >> shift) & 0xFFu], 1u);
        }
        __syncthreads();
        if (tid == 0) {
            int cum = 0, b;
            for (b = 255; b >= 0; b--) {
                int c = (int)hist[b];
                if (cum + c >= remaining) break;
                cum += c;
            }
            if (b < 0) b = 0;
            *p_prefix = prefix | ((uint32_t)b << shift);
            *p_remaining = remaining - cum;
        }
        __syncthreads();
        prefix = *p_prefix;
        remaining = *p_remaining;
        __syncthreads();
    }
    const uint32_t thresh = prefix;
    const int need_eq = remaining;

    // 2) gather strictly-greater entries (count = 50 - need_eq)
    if (tid == 0) *p_ntop = 0;
    __syncthreads();
    for (int v = tid; v < V; v += BLOCK) {
        float x = lg[v];
        if (fkey(x) > thresh) {
            int p = atomicAdd(p_ntop, 1);
            tv[p] = x; ti[p] = v;
        }
    }
    __syncthreads();
    const int base = *p_ntop;
    // equal-to-threshold entries, ascending index (lax.top_k tie-break)
    int last = -1;
    for (int j = 0; j < need_eq; j++) {
        int best = V;
        for (int v = tid; v < V; v += BLOCK) {
            if (v > last && fkey(lg[v]) == thresh) { best = v; break; }
        }
        red[tid] = best;
        __syncthreads();
        for (int s = BLOCK / 2; s > 0; s >>= 1) {
            if (tid < s) red[tid] = min(red[tid], red[tid + s]);
            __syncthreads();
        }
        int found = red[0];
        if (tid == 0) { tv[base + j] = lg[found]; ti[base + j] = found; }
        last = found;
        __syncthreads();
    }

    // 3) single-thread epilogue: sort 50, softmax+top-p, gumbel-argmax
    if (tid == 0) {
        for (int i = 1; i < TOPK; i++) {
            float v = tv[i]; int id = ti[i];
            int j = i - 1;
            while (j >= 0 && (tv[j] < v || (tv[j] == v && ti[j] > id))) {
                tv[j + 1] = tv[j]; ti[j + 1] = ti[j]; j--;
            }
            tv[j + 1] = v; ti[j + 1] = id;
        }
        float m = tv[0];
        float sum = 0.0f;
        for (int i = 0; i < TOPK; i++) sum += expf(tv[i] - m);
        const unsigned long long total = (unsigned long long)rows * (unsigned long long)V;
        float cum = 0.0f;
        float best = -INFINITY;
        int bestv = 0x7fffffff;
        for (int i = 0; i < TOPK; i++) {
            bool keep = (i == 0) || (cum <= TOPP);
            cum += expf(tv[i] - m) / sum;
            if (!keep) continue;
            unsigned long long flat = (unsigned long long)row * (unsigned long long)V
                                      + (unsigned long long)ti[i];
            float g = gumbel_at(flat, total);
            float s = tv[i] + g;
            if (s > best || (s == best && ti[i] < bestv)) { best = s; bestv = ti[i]; }
        }
        out[row] = bestv;
    }
    __syncthreads();
}

__global__ __launch_bounds__(BLOCK)
void rd_kernel(const float* __restrict__ logits, const int* __restrict__ x_t,
               int* __restrict__ out, int V, int rows) {
    const int tid = threadIdx.x;
    const int rpb = (rows + gridDim.x - 1) / gridDim.x;   // 32
    const int r0 = blockIdx.x * rpb;
    const int r1 = min(rows, r0 + rpb);

    __shared__ int masked[64];
    __shared__ int nmask;
    __shared__ uint32_t hist[256];
    __shared__ int red[BLOCK];
    __shared__ float tv[TOPK];
    __shared__ int ti[TOPK];
    __shared__ uint32_t s_prefix;
    __shared__ int s_remaining, s_ntop;

    if (tid == 0) nmask = 0;
    __syncthreads();

    // fast path: copy x_t -> out, record masked rows
    for (int r = r0 + tid; r < r1; r += BLOCK) {
        int xv = x_t[r];
        out[r] = xv;
        if (xv == MASK_ID) { int p = atomicAdd(&nmask, 1); masked[p] = r; }
    }
    __syncthreads();

    // rare path: block-cooperative exact sampling per masked row
    const int nm = nmask;
    for (int m = 0; m < nm; m++) {
        const int row = masked[m];
        process_row(logits + (size_t)row * (size_t)V, row, V, rows, out,
                    hist, red, tv, ti, &s_prefix, &s_remaining, &s_ntop);
    }
}

extern "C" void kernel_launch(void* const* d_in, const int* in_sizes, int n_in,
                              void* d_out, int out_size, void* d_ws, size_t ws_size,
                              hipStream_t stream) {
    const float* logits = (const float*)d_in[0];
    const int*   x_t    = (const int*)d_in[1];
    int*         out    = (int*)d_out;
    const int rows = in_sizes[1];                 // B*S = 2048
    const int V    = in_sizes[0] / rows;          // 50257
    rd_kernel<<<GRID, BLOCK, 0, stream>>>(logits, x_t, out, V, rows);
}